// Round 17
// baseline (145.685 us; speedup 1.0000x reference)
//
#include <hip/hip_runtime.h>
#include <stdint.h>

typedef __attribute__((ext_vector_type(8))) short bf16x8;
typedef __attribute__((ext_vector_type(16))) float f32x16;

#define MFMA32(a, b, c) __builtin_amdgcn_mfma_f32_32x32x16_bf16(a, b, c, 0, 0, 0)

// Problem constants
#define BB 4
#define TT 2048
#define CC 576
#define NH 9
#define NKV 3
#define HD 64
#define MM (BB * TT)          // 8192
#define NQKV 960              // 576 + 192 + 192

// 0.125 (1/sqrt(64)) * log2(e), folded into Q so attention runs in exp2 domain
#define QSC 0.18033688011112042f

__device__ __forceinline__ unsigned short f2bf(float f) {
  union { float f; uint32_t u; } v; v.f = f;
  uint32_t u = v.u;
  uint32_t r = (u + 0x7fffu + ((u >> 16) & 1u)) >> 16;
  return (unsigned short)r;
}

__device__ __forceinline__ void gl16(const void* g, void* l) {
  __builtin_amdgcn_global_load_lds(
      (const __attribute__((address_space(1))) unsigned int*)g,
      (__attribute__((address_space(3))) unsigned int*)l, 16, 0, 0);
}

__device__ __forceinline__ float fexp2(float x) {
  float r;
  asm("v_exp_f32 %0, %1" : "=v"(r) : "v"(x));
  return r;
}

// ---------------------------------------------------------------------------
// Prep: f32 -> bf16 conversions (vectorized) + RoPE cos/sin table
// ---------------------------------------------------------------------------
__global__ __launch_bounds__(256) void prep_kernel(
    const float* __restrict__ x, const float* __restrict__ wq,
    const float* __restrict__ wk, const float* __restrict__ wv,
    const float* __restrict__ wo,
    unsigned short* __restrict__ xh, unsigned short* __restrict__ wqkv,
    unsigned short* __restrict__ woh, float* __restrict__ tc,
    float* __restrict__ ts) {
  const int NX4 = MM * CC / 4;
  const int NW4 = NQKV * CC / 4;
  const int NO4 = CC * CC / 4;
  const int NT = TT * 32;
  const int total = NX4 + NW4 + NO4 + NT;
  for (int i = blockIdx.x * blockDim.x + threadIdx.x; i < total;
       i += gridDim.x * blockDim.x) {
    if (i < NX4) {
      float4 v = ((const float4*)x)[i];
      ushort4 o;
      o.x = f2bf(v.x); o.y = f2bf(v.y); o.z = f2bf(v.z); o.w = f2bf(v.w);
      ((ushort4*)xh)[i] = o;
    } else if (i < NX4 + NW4) {
      int j = i - NX4;
      int n = (j * 4) / CC;
      const float* src = (n < 576) ? wq + j * 4
                       : (n < 768) ? wk + j * 4 - 576 * CC
                                   : wv + j * 4 - 768 * CC;
      float4 v = *(const float4*)src;
      ushort4 o;
      o.x = f2bf(v.x); o.y = f2bf(v.y); o.z = f2bf(v.z); o.w = f2bf(v.w);
      ((ushort4*)wqkv)[j] = o;
    } else if (i < NX4 + NW4 + NO4) {
      int j = i - NX4 - NW4;
      float4 v = ((const float4*)wo)[j];
      ushort4 o;
      o.x = f2bf(v.x); o.y = f2bf(v.y); o.z = f2bf(v.z); o.w = f2bf(v.w);
      ((ushort4*)woh)[j] = o;
    } else {
      int j = i - NX4 - NW4 - NO4;
      int t = j >> 5, pi = j & 31;
      double invf = pow(100000.0, -(double)(2 * pi) / 64.0);
      double ang = (double)t * invf;
      tc[j] = (float)cos(ang);
      ts[j] = (float)sin(ang);
    }
  }
}

// ---------------------------------------------------------------------------
// GEMM1: BM=256 BN=64 BK=64, 8 waves, staged via global_load_lds into
// XOR-swizzled LDS image, double-buffered, counted vmcnt(5).
// Epilogue: RoPE + scatter; K/V tiles written FRAGMENT-MAJOR:
//   K tile (head, jt): seg(ds=d>>4, rh=t>>5) at (ds*2+rh)*512 shorts;
//     elem K[t][d] -> seg + (((d>>3)&1)*32 + (t&31))*8 + (d&7)
//   V tile: seg(ks=tt>>4, dh=d>>5) at (ks*2+dh)*512 shorts;
//     elem V[t][d] -> seg + (((tt>>3)&1)*32 + (d&31))*8 + (tt&7)
// so attention lane l's bf16x8 operand = contiguous 16B at seg + l*16.
// ---------------------------------------------------------------------------
__global__ __launch_bounds__(512, 4) void gemm_qkv(
    const unsigned short* __restrict__ xh, const unsigned short* __restrict__ wqkv,
    const float* __restrict__ tc, const float* __restrict__ ts,
    unsigned short* __restrict__ qb, unsigned short* __restrict__ kst,
    unsigned short* __restrict__ vst) {
  const int l = threadIdx.x & 63, w = threadIdx.x >> 6;  // w in 0..7
  const int ln = l & 31, hi = l >> 5;
  const int bm = blockIdx.y * 256, bn = blockIdx.x * 64;

  __shared__ unsigned short als[2][16384];  // 256x64 per buf
  __shared__ unsigned short bls[2][4096];   // 64x64 per buf

  int asrc[4];
#pragma unroll
  for (int i = 0; i < 4; ++i)
    asrc[i] = (bm + w * 32 + i * 8 + (l >> 3)) * CC + ((l & 7) ^ ((l >> 3) & 7)) * 8;
  const int bsrc = (bn + w * 8 + (l >> 3)) * CC + ((l & 7) ^ ((l >> 3) & 7)) * 8;

  f32x16 acc0, acc1;
#pragma unroll
  for (int r = 0; r < 16; ++r) { acc0[r] = 0.f; acc1[r] = 0.f; }

#pragma unroll
  for (int i = 0; i < 4; ++i) gl16(xh + asrc[i], (char*)&als[0][0] + w * 4096 + i * 1024);
  gl16(wqkv + bsrc, (char*)&bls[0][0] + w * 1024);

  int cur = 0;
  for (int t = 0; t < 9; ++t) {
    if (t + 1 < 9) {
      const int k0 = (t + 1) * 64;
#pragma unroll
      for (int i = 0; i < 4; ++i)
        gl16(xh + asrc[i] + k0, (char*)&als[cur ^ 1][0] + w * 4096 + i * 1024);
      gl16(wqkv + bsrc + k0, (char*)&bls[cur ^ 1][0] + w * 1024);
      asm volatile("s_waitcnt vmcnt(5)" ::: "memory");
    } else {
      asm volatile("s_waitcnt vmcnt(0)" ::: "memory");
    }
    __builtin_amdgcn_s_barrier();
    __builtin_amdgcn_sched_barrier(0);

    const char* ab = (const char*)&als[cur][0];
    const char* bb = (const char*)&bls[cur][0];
    __builtin_amdgcn_s_setprio(1);
#pragma unroll
    for (int ks = 0; ks < 4; ++ks) {
      const int ch = (((ks * 2 + hi) ^ (ln & 7)) << 4);
      bf16x8 af = *(const bf16x8*)(ab + (w * 32 + ln) * 128 + ch);
      bf16x8 b0 = *(const bf16x8*)(bb + ln * 128 + ch);
      bf16x8 b1 = *(const bf16x8*)(bb + (32 + ln) * 128 + ch);
      acc0 = MFMA32(af, b0, acc0);
      acc1 = MFMA32(af, b1, acc1);
    }
    __builtin_amdgcn_s_setprio(0);

    __builtin_amdgcn_sched_barrier(0);
    __builtin_amdgcn_s_barrier();
    cur ^= 1;
  }

#pragma unroll
  for (int n32 = 0; n32 < 2; ++n32) {
    const int col = bn + n32 * 32 + ln;
    const int d = col & 63;
#pragma unroll
    for (int r = 0; r < 16; ++r) {
      const int m = bm + w * 32 + (r & 3) + 8 * (r >> 2) + 4 * hi;
      float v = n32 ? acc1[r] : acc0[r];
      float partner = __shfl_xor(v, 1);
      const int bi = m >> 11, t = m & 2047;
      if (col < 768) {  // RoPE for q and k
        const int pi = d >> 1;
        const float c = tc[t * 32 + pi], s = ts[t * 32 + pi];
        v = (d & 1) ? (partner * s + v * c) : (v * c - partner * s);
      }
      if (col < 576) {
        const int h = col >> 6;
        qb[(((size_t)bi * NH + h) * TT + t) * HD + d] = f2bf(v * QSC);
      } else if (col < 768) {
        const int h = (col - 576) >> 6;
        const size_t head = (size_t)bi * NKV + h;
        const int tt = t & 63;
        kst[(head * 32 + (t >> 6)) * 4096 + ((d >> 4) * 2 + (tt >> 5)) * 512
            + ((((d >> 3) & 1) << 5) + (tt & 31)) * 8 + (d & 7)] = f2bf(v);
      } else {
        const int h = (col - 768) >> 6;
        const size_t head = (size_t)bi * NKV + h;
        const int tt = t & 63;
        vst[(head * 32 + (t >> 6)) * 4096 + ((tt >> 4) * 2 + (d >> 5)) * 512
            + ((((tt >> 3) & 1) << 5) + (d & 31)) * 8 + (tt & 7)] = f2bf(v);
      }
    }
  }
}

// ---------------------------------------------------------------------------
// Flash attention v17: maximum stream count. Block = 4 waves x 128 q-rows;
// ALL waves share one staged K/V tile per iteration (K 8KB + V 8KB,
// double-buffered = exactly 32KB LDS -> 5 blocks/CU co-resident).
// No parity split, no combine, no epilogue. Grid (16, 9, 4) = 576 blocks,
// big-first (qt = 15-x) for backfill balance. Wave-uniform skip elides
// compute on fully-masked tiles. Fragment-major LDS reads (0 conflicts),
// static-max softmax, per-wave direct yb write.
// ---------------------------------------------------------------------------
__global__ __launch_bounds__(256, 5) void attn_kernel(
    const unsigned short* __restrict__ qbuf, const unsigned short* __restrict__ kst,
    const unsigned short* __restrict__ vst, unsigned short* __restrict__ yb) {
  const int qt = 15 - blockIdx.x, h = blockIdx.y, b = blockIdx.z;
  const int l = threadIdx.x & 63, wq = threadIdx.x >> 6;  // wq in {0,1,2,3}
  const int ln = l & 31, hb = l >> 5;
  const int kvh = h / 3;
  const size_t head = (size_t)b * NKV + kvh;
  const int nt = 2 * qt + 2;

  __shared__ unsigned short kls[2][4096];
  __shared__ unsigned short vls[2][4096];

  const unsigned short* qptr = qbuf + ((size_t)b * NH + h) * TT * HD;
  const int qrow = qt * 128 + wq * 32 + ln;
  const int wmax = qt * 128 + wq * 32 + 31;   // wave's max q-row

  bf16x8 qc[4];
#pragma unroll
  for (int ds = 0; ds < 4; ++ds)
    qc[ds] = *(const bf16x8*)(qptr + (size_t)qrow * HD + ds * 16 + hb * 8);

  const char* kgb = (const char*)(kst + head * 32 * 4096);
  const char* vgb = (const char*)(vst + head * 32 * 4096);

  f32x16 o0, o1, fzero;
  float ls[16];
#pragma unroll
  for (int r = 0; r < 16; ++r) { o0[r] = 0.f; o1[r] = 0.f; ls[r] = 0.f; fzero[r] = 0.f; }

  // prologue: stage kv tile 0 into buf 0 (each wave: 2KB of K + 2KB of V)
#pragma unroll
  for (int i2 = 0; i2 < 2; ++i2) {
    const int off = wq * 2048 + i2 * 1024;
    gl16(kgb + off + l * 16, (char*)&kls[0][0] + off);
    gl16(vgb + off + l * 16, (char*)&vls[0][0] + off);
  }

  for (int u = 0; u < nt; ++u) {
    if (u + 1 < nt) {  // stage next tile into other buf (1-ahead)
      const size_t tb = (size_t)(u + 1) * 8192;
      char* kl = (char*)&kls[(u + 1) & 1][0];
      char* vl = (char*)&vls[(u + 1) & 1][0];
#pragma unroll
      for (int i2 = 0; i2 < 2; ++i2) {
        const int off = wq * 2048 + i2 * 1024;
        gl16(kgb + tb + off + l * 16, kl + off);
        gl16(vgb + tb + off + l * 16, vl + off);
      }
      asm volatile("s_waitcnt vmcnt(4)" ::: "memory");  // stage(u) done (mine)
    } else {
      asm volatile("s_waitcnt vmcnt(0)" ::: "memory");
    }
    __builtin_amdgcn_s_barrier();          // everyone's stage(u) landed
    __builtin_amdgcn_sched_barrier(0);

    if (64 * u <= wmax) {  // wave-uniform: skip fully-masked tiles
      const char* kb = (const char*)&kls[u & 1][0];
      const char* vb = (const char*)&vls[u & 1][0];

      // QK^T swapped: S^T[k, q]; fragment-major reads (seg base + l*16)
      f32x16 s0, s1;
      __builtin_amdgcn_s_setprio(1);
      {
        bf16x8 k0 = *(const bf16x8*)(kb + 0 * 1024 + l * 16);
        bf16x8 k1 = *(const bf16x8*)(kb + 1 * 1024 + l * 16);
        s0 = MFMA32(k0, qc[0], fzero);
        s1 = MFMA32(k1, qc[0], fzero);
      }
#pragma unroll
      for (int ds = 1; ds < 4; ++ds) {
        bf16x8 k0 = *(const bf16x8*)(kb + (ds * 2 + 0) * 1024 + l * 16);
        bf16x8 k1 = *(const bf16x8*)(kb + (ds * 2 + 1) * 1024 + l * 16);
        s0 = MFMA32(k0, qc[ds], s0);
        s1 = MFMA32(k1, qc[ds], s1);
      }
      __builtin_amdgcn_s_setprio(0);

      if (u >= 2 * qt) {  // diagonal region: causal mask (elementwise)
#pragma unroll
        for (int r = 0; r < 16; ++r) {
          const int kg = u * 64 + (r & 3) + 8 * (r >> 2) + 4 * hb;
          if (kg > qrow) s0[r] = -1e30f;
          if (kg + 32 > qrow) s1[r] = -1e30f;
        }
      }

      // static-max softmax: P = exp2(S) directly; masked -> 0
#pragma unroll
      for (int r = 0; r < 16; ++r) {
        s0[r] = fexp2(s0[r]);
        s1[r] = fexp2(s1[r]);
      }
#pragma unroll
      for (int r = 0; r < 16; ++r) ls[r] += s0[r] + s1[r];

      // pack P -> PV A-fragments: 16 cvt_pk + 8 permlane32_swap
      unsigned int pa[4][4];
#pragma unroll
      for (int t = 0; t < 2; ++t) {
#pragma unroll
        for (int m = 0; m < 2; ++m) {
          float p0 = t ? s1[8 * m + 0] : s0[8 * m + 0];
          float p1 = t ? s1[8 * m + 1] : s0[8 * m + 1];
          float p2 = t ? s1[8 * m + 2] : s0[8 * m + 2];
          float p3 = t ? s1[8 * m + 3] : s0[8 * m + 3];
          float p4 = t ? s1[8 * m + 4] : s0[8 * m + 4];
          float p5 = t ? s1[8 * m + 5] : s0[8 * m + 5];
          float p6 = t ? s1[8 * m + 6] : s0[8 * m + 6];
          float p7 = t ? s1[8 * m + 7] : s0[8 * m + 7];
          unsigned int w0, w1, w2, w3;
          asm("v_cvt_pk_bf16_f32 %0, %1, %2" : "=v"(w0) : "v"(p0), "v"(p1));
          asm("v_cvt_pk_bf16_f32 %0, %1, %2" : "=v"(w1) : "v"(p2), "v"(p3));
          asm("v_cvt_pk_bf16_f32 %0, %1, %2" : "=v"(w2) : "v"(p4), "v"(p5));
          asm("v_cvt_pk_bf16_f32 %0, %1, %2" : "=v"(w3) : "v"(p6), "v"(p7));
          asm("v_permlane32_swap_b32 %0, %1" : "+v"(w0), "+v"(w2));
          asm("v_permlane32_swap_b32 %0, %1" : "+v"(w1), "+v"(w3));
          pa[2 * t + m][0] = w0; pa[2 * t + m][1] = w1;
          pa[2 * t + m][2] = w2; pa[2 * t + m][3] = w3;
        }
      }

      // PV: fragment-major reads
      __builtin_amdgcn_s_setprio(1);
#pragma unroll
      for (int ks = 0; ks < 4; ++ks) {
        union { unsigned int u[4]; bf16x8 v; } cvt;
        cvt.u[0] = pa[ks][0]; cvt.u[1] = pa[ks][1];
        cvt.u[2] = pa[ks][2]; cvt.u[3] = pa[ks][3];
        bf16x8 v0 = *(const bf16x8*)(vb + (ks * 2 + 0) * 1024 + l * 16);
        bf16x8 v1 = *(const bf16x8*)(vb + (ks * 2 + 1) * 1024 + l * 16);
        o0 = MFMA32(cvt.v, v0, o0);
        o1 = MFMA32(cvt.v, v1, o1);
      }
      __builtin_amdgcn_s_setprio(0);
    }

    __builtin_amdgcn_sched_barrier(0);
    __builtin_amdgcn_s_barrier();          // readers done before next overwrite
    __builtin_amdgcn_sched_barrier(0);
  }

  // per-wave epilogue: reduce li, normalize + write
#pragma unroll
  for (int st = 8; st >= 1; st >>= 1)
#pragma unroll
    for (int r = 0; r < 8; ++r)
      if (r < st) ls[r] += ls[r + st];
  const float li = ls[0] + __shfl_xor(ls[0], 32);
  const float inv = 1.0f / li;
#pragma unroll
  for (int r = 0; r < 16; ++r) {
    const int cr = (r & 3) + 8 * (r >> 2) + 4 * hb;
    const float ir = __shfl(inv, cr);
    const int t = qt * 128 + wq * 32 + cr;
    unsigned short* yp = yb + ((size_t)b * TT + t) * CC + h * HD;
    yp[ln] = f2bf(o0[r] * ir);
    yp[32 + ln] = f2bf(o1[r] * ir);
  }
}

// ---------------------------------------------------------------------------
// GEMM2: BM=256 BN=64, 8 waves, staged structure; f32 epilogue.
// ---------------------------------------------------------------------------
__global__ __launch_bounds__(512, 4) void gemm_out(
    const unsigned short* __restrict__ yb, const unsigned short* __restrict__ woh,
    float* __restrict__ out) {
  const int l = threadIdx.x & 63, w = threadIdx.x >> 6;
  const int ln = l & 31, hi = l >> 5;
  const int bm = blockIdx.y * 256, bn = blockIdx.x * 64;

  __shared__ unsigned short als[2][16384];
  __shared__ unsigned short bls[2][4096];

  int asrc[4];
#pragma unroll
  for (int i = 0; i < 4; ++i)
    asrc[i] = (bm + w * 32 + i * 8 + (l >> 3)) * CC + ((l & 7) ^ ((l >> 3) & 7)) * 8;
  const int bsrc = (bn + w * 8 + (l >> 3)) * CC + ((l & 7) ^ ((l >> 3) & 7)) * 8;

  f32x16 acc0, acc1;
#pragma unroll
  for (int r = 0; r < 16; ++r) { acc0[r] = 0.f; acc1[r] = 0.f; }

#pragma unroll
  for (int i = 0; i < 4; ++i) gl16(yb + asrc[i], (char*)&als[0][0] + w * 4096 + i * 1024);
  gl16(woh + bsrc, (char*)&bls[0][0] + w * 1024);

  int cur = 0;
  for (int t = 0; t < 9; ++t) {
    if (t + 1 < 9) {
      const int k0 = (t + 1) * 64;
#pragma unroll
      for (int i = 0; i < 4; ++i)
        gl16(yb + asrc[i] + k0, (char*)&als[cur ^ 1][0] + w * 4096 + i * 1024);
      gl16(woh + bsrc + k0, (char*)&bls[cur ^ 1][0] + w * 1024);
      asm volatile("s_waitcnt vmcnt(5)" ::: "memory");
    } else {
      asm volatile("s_waitcnt vmcnt(0)" ::: "memory");
    }
    __builtin_amdgcn_s_barrier();
    __builtin_amdgcn_sched_barrier(0);

    const char* ab = (const char*)&als[cur][0];
    const char* bb = (const char*)&bls[cur][0];
    __builtin_amdgcn_s_setprio(1);
#pragma unroll
    for (int ks = 0; ks < 4; ++ks) {
      const int ch = (((ks * 2 + hi) ^ (ln & 7)) << 4);
      bf16x8 af = *(const bf16x8*)(ab + (w * 32 + ln) * 128 + ch);
      bf16x8 b0 = *(const bf16x8*)(bb + ln * 128 + ch);
      bf16x8 b1 = *(const bf16x8*)(bb + (32 + ln) * 128 + ch);
      acc0 = MFMA32(af, b0, acc0);
      acc1 = MFMA32(af, b1, acc1);
    }
    __builtin_amdgcn_s_setprio(0);

    __builtin_amdgcn_sched_barrier(0);
    __builtin_amdgcn_s_barrier();
    cur ^= 1;
  }

#pragma unroll
  for (int n32 = 0; n32 < 2; ++n32) {
    const int col = bn + n32 * 32 + ln;
#pragma unroll
    for (int r = 0; r < 16; ++r) {
      const int m = bm + w * 32 + (r & 3) + 8 * (r >> 2) + 4 * hi;
      out[(size_t)m * CC + col] = n32 ? acc1[r] : acc0[r];
    }
  }
}

// ---------------------------------------------------------------------------
extern "C" void kernel_launch(void* const* d_in, const int* in_sizes, int n_in,
                              void* d_out, int out_size, void* d_ws, size_t ws_size,
                              hipStream_t stream) {
  const float* x = (const float*)d_in[0];
  const float* wq = (const float*)d_in[1];
  const float* wk = (const float*)d_in[2];
  const float* wv = (const float*)d_in[3];
  const float* wo = (const float*)d_in[4];
  float* out = (float*)d_out;

  char* ws = (char*)d_ws;
  unsigned short* xh = (unsigned short*)ws;    ws += (size_t)MM * CC * 2;
  unsigned short* wqkv = (unsigned short*)ws;  ws += (size_t)NQKV * CC * 2;
  float* tc = (float*)ws;                      ws += (size_t)TT * 32 * 4;
  float* tsn = (float*)ws;                     ws += (size_t)TT * 32 * 4;
  unsigned short* woh = (unsigned short*)ws;   ws += (size_t)CC * CC * 2;
  unsigned short* qbuf = (unsigned short*)ws;  ws += (size_t)BB * NH * TT * HD * 2;
  unsigned short* kst = (unsigned short*)ws;   ws += (size_t)BB * NKV * TT * HD * 2;
  unsigned short* vst = (unsigned short*)ws;   ws += (size_t)BB * NKV * HD * TT * 2;
  unsigned short* yb = (unsigned short*)ws;    ws += (size_t)MM * CC * 2;

  prep_kernel<<<dim3(2048), dim3(256), 0, stream>>>(x, wq, wk, wv, wo, xh, wqkv, woh, tc, tsn);
  gemm_qkv<<<dim3(NQKV / 64, MM / 256), dim3(512), 0, stream>>>(xh, wqkv, tc, tsn, qbuf, kst, vst);
  attn_kernel<<<dim3(16, NH, BB), dim3(256), 0, stream>>>(qbuf, kst, vst, yb);
  gemm_out<<<dim3(CC / 64, MM / 256), dim3(512), 0, stream>>>(yb, woh, out);
}

// Round 18
// 98.873 us; speedup vs baseline: 1.4735x; 1.4735x over previous
//
#include <hip/hip_runtime.h>
#include <stdint.h>

typedef __attribute__((ext_vector_type(8))) short bf16x8;
typedef __attribute__((ext_vector_type(16))) float f32x16;

#define MFMA32(a, b, c) __builtin_amdgcn_mfma_f32_32x32x16_bf16(a, b, c, 0, 0, 0)

// Problem constants
#define BB 4
#define TT 2048
#define CC 576
#define NH 9
#define NKV 3
#define HD 64
#define MM (BB * TT)          // 8192
#define NQKV 960              // 576 + 192 + 192

// 0.125 (1/sqrt(64)) * log2(e), folded into Q so attention runs in exp2 domain
#define QSC 0.18033688011112042f

__device__ __forceinline__ unsigned short f2bf(float f) {
  union { float f; uint32_t u; } v; v.f = f;
  uint32_t u = v.u;
  uint32_t r = (u + 0x7fffu + ((u >> 16) & 1u)) >> 16;
  return (unsigned short)r;
}

__device__ __forceinline__ void gl16(const void* g, void* l) {
  __builtin_amdgcn_global_load_lds(
      (const __attribute__((address_space(1))) unsigned int*)g,
      (__attribute__((address_space(3))) unsigned int*)l, 16, 0, 0);
}

__device__ __forceinline__ float fexp2(float x) {
  float r;
  asm("v_exp_f32 %0, %1" : "=v"(r) : "v"(x));
  return r;
}

// ---------------------------------------------------------------------------
// Prep: f32 -> bf16 conversions (vectorized) + RoPE cos/sin table
// ---------------------------------------------------------------------------
__global__ __launch_bounds__(256) void prep_kernel(
    const float* __restrict__ x, const float* __restrict__ wq,
    const float* __restrict__ wk, const float* __restrict__ wv,
    const float* __restrict__ wo,
    unsigned short* __restrict__ xh, unsigned short* __restrict__ wqkv,
    unsigned short* __restrict__ woh, float* __restrict__ tc,
    float* __restrict__ ts) {
  const int NX4 = MM * CC / 4;
  const int NW4 = NQKV * CC / 4;
  const int NO4 = CC * CC / 4;
  const int NT = TT * 32;
  const int total = NX4 + NW4 + NO4 + NT;
  for (int i = blockIdx.x * blockDim.x + threadIdx.x; i < total;
       i += gridDim.x * blockDim.x) {
    if (i < NX4) {
      float4 v = ((const float4*)x)[i];
      ushort4 o;
      o.x = f2bf(v.x); o.y = f2bf(v.y); o.z = f2bf(v.z); o.w = f2bf(v.w);
      ((ushort4*)xh)[i] = o;
    } else if (i < NX4 + NW4) {
      int j = i - NX4;
      int n = (j * 4) / CC;
      const float* src = (n < 576) ? wq + j * 4
                       : (n < 768) ? wk + j * 4 - 576 * CC
                                   : wv + j * 4 - 768 * CC;
      float4 v = *(const float4*)src;
      ushort4 o;
      o.x = f2bf(v.x); o.y = f2bf(v.y); o.z = f2bf(v.z); o.w = f2bf(v.w);
      ((ushort4*)wqkv)[j] = o;
    } else if (i < NX4 + NW4 + NO4) {
      int j = i - NX4 - NW4;
      float4 v = ((const float4*)wo)[j];
      ushort4 o;
      o.x = f2bf(v.x); o.y = f2bf(v.y); o.z = f2bf(v.z); o.w = f2bf(v.w);
      ((ushort4*)woh)[j] = o;
    } else {
      int j = i - NX4 - NW4 - NO4;
      int t = j >> 5, pi = j & 31;
      double invf = pow(100000.0, -(double)(2 * pi) / 64.0);
      double ang = (double)t * invf;
      tc[j] = (float)cos(ang);
      ts[j] = (float)sin(ang);
    }
  }
}

// ---------------------------------------------------------------------------
// GEMM1: BM=256 BN=64 BK=64, 8 waves, staged via global_load_lds into
// XOR-swizzled LDS image, double-buffered, counted vmcnt(5).
// Epilogue: RoPE + scatter. K/V tiles written FRAGMENT-MAJOR:
//   K tile (head, jt): seg(ds=d>>4, rh=t>>5) at (ds*2+rh)*512 shorts;
//     elem K[t][d] -> seg + (((d>>3)&1)*32 + (t&31))*8 + (d&7)
//   V tile: seg(ks=tt>>4, dh=d>>5) at (ks*2+dh)*512 shorts;
//     elem V[t][d] -> seg + (((tt>>3)&1)*32 + (d&31))*8 + (tt&7)
// so attention lane l's bf16x8 operand = contiguous 16B at seg + l*16.
// ---------------------------------------------------------------------------
__global__ __launch_bounds__(512, 4) void gemm_qkv(
    const unsigned short* __restrict__ xh, const unsigned short* __restrict__ wqkv,
    const float* __restrict__ tc, const float* __restrict__ ts,
    unsigned short* __restrict__ qb, unsigned short* __restrict__ kst,
    unsigned short* __restrict__ vst) {
  const int l = threadIdx.x & 63, w = threadIdx.x >> 6;  // w in 0..7
  const int ln = l & 31, hi = l >> 5;
  const int bm = blockIdx.y * 256, bn = blockIdx.x * 64;

  __shared__ unsigned short als[2][16384];  // 256x64 per buf
  __shared__ unsigned short bls[2][4096];   // 64x64 per buf

  int asrc[4];
#pragma unroll
  for (int i = 0; i < 4; ++i)
    asrc[i] = (bm + w * 32 + i * 8 + (l >> 3)) * CC + ((l & 7) ^ ((l >> 3) & 7)) * 8;
  const int bsrc = (bn + w * 8 + (l >> 3)) * CC + ((l & 7) ^ ((l >> 3) & 7)) * 8;

  f32x16 acc0, acc1;
#pragma unroll
  for (int r = 0; r < 16; ++r) { acc0[r] = 0.f; acc1[r] = 0.f; }

#pragma unroll
  for (int i = 0; i < 4; ++i) gl16(xh + asrc[i], (char*)&als[0][0] + w * 4096 + i * 1024);
  gl16(wqkv + bsrc, (char*)&bls[0][0] + w * 1024);

  int cur = 0;
  for (int t = 0; t < 9; ++t) {
    if (t + 1 < 9) {
      const int k0 = (t + 1) * 64;
#pragma unroll
      for (int i = 0; i < 4; ++i)
        gl16(xh + asrc[i] + k0, (char*)&als[cur ^ 1][0] + w * 4096 + i * 1024);
      gl16(wqkv + bsrc + k0, (char*)&bls[cur ^ 1][0] + w * 1024);
      asm volatile("s_waitcnt vmcnt(5)" ::: "memory");
    } else {
      asm volatile("s_waitcnt vmcnt(0)" ::: "memory");
    }
    __builtin_amdgcn_s_barrier();
    __builtin_amdgcn_sched_barrier(0);

    const char* ab = (const char*)&als[cur][0];
    const char* bb = (const char*)&bls[cur][0];
    __builtin_amdgcn_s_setprio(1);
#pragma unroll
    for (int ks = 0; ks < 4; ++ks) {
      const int ch = (((ks * 2 + hi) ^ (ln & 7)) << 4);
      bf16x8 af = *(const bf16x8*)(ab + (w * 32 + ln) * 128 + ch);
      bf16x8 b0 = *(const bf16x8*)(bb + ln * 128 + ch);
      bf16x8 b1 = *(const bf16x8*)(bb + (32 + ln) * 128 + ch);
      acc0 = MFMA32(af, b0, acc0);
      acc1 = MFMA32(af, b1, acc1);
    }
    __builtin_amdgcn_s_setprio(0);

    __builtin_amdgcn_sched_barrier(0);
    __builtin_amdgcn_s_barrier();
    cur ^= 1;
  }

#pragma unroll
  for (int n32 = 0; n32 < 2; ++n32) {
    const int col = bn + n32 * 32 + ln;
    const int d = col & 63;
#pragma unroll
    for (int r = 0; r < 16; ++r) {
      const int m = bm + w * 32 + (r & 3) + 8 * (r >> 2) + 4 * hi;
      float v = n32 ? acc1[r] : acc0[r];
      float partner = __shfl_xor(v, 1);
      const int bi = m >> 11, t = m & 2047;
      if (col < 768) {  // RoPE for q and k
        const int pi = d >> 1;
        const float c = tc[t * 32 + pi], s = ts[t * 32 + pi];
        v = (d & 1) ? (partner * s + v * c) : (v * c - partner * s);
      }
      if (col < 576) {
        const int h = col >> 6;
        qb[(((size_t)bi * NH + h) * TT + t) * HD + d] = f2bf(v * QSC);
      } else if (col < 768) {
        const int h = (col - 576) >> 6;
        const size_t head = (size_t)bi * NKV + h;
        const int tt = t & 63;
        kst[(head * 32 + (t >> 6)) * 4096 + ((d >> 4) * 2 + (tt >> 5)) * 512
            + ((((d >> 3) & 1) << 5) + (tt & 31)) * 8 + (d & 7)] = f2bf(v);
      } else {
        const int h = (col - 768) >> 6;
        const size_t head = (size_t)bi * NKV + h;
        const int tt = t & 63;
        vst[(head * 32 + (t >> 6)) * 4096 + ((tt >> 4) * 2 + (d >> 5)) * 512
            + ((((tt >> 3) & 1) << 5) + (d & 31)) * 8 + (tt & 7)] = f2bf(v);
      }
    }
  }
}

// ---------------------------------------------------------------------------
// Flash attention v15 (banked best): 2-blocks/CU occupancy. LDS 65KB
// (double-buffered K/V per parity group, 1-ahead staging, 2 barriers/iter);
// grid 468 (13 bins/head: singles qt=15..7, pairs {6,0},{5,1},{4,2},
// single {3}; big bins first). 8 waves = 2 KV-parity groups x 4 q-waves,
// fragment-major LDS reads (zero bank conflicts), static-max softmax,
// segment-end combine via the consumed stage buffers.
// ---------------------------------------------------------------------------
__global__ __launch_bounds__(512, 4) void attn_kernel(
    const unsigned short* __restrict__ qbuf, const unsigned short* __restrict__ kst,
    const unsigned short* __restrict__ vst, unsigned short* __restrict__ yb) {
  const int jx = blockIdx.x, kvh = blockIdx.y, b = blockIdx.z;
  const int j = jx % 13, hr = jx / 13;
  const int h = kvh * 3 + hr;
  const int l = threadIdx.x & 63;
  const int w8 = threadIdx.x >> 6;   // 0..7
  const int g = w8 >> 2;             // kv-parity group
  const int wq = w8 & 3;             // q-wave within group
  const int ln = l & 31, hi = l >> 5;
  const size_t head = (size_t)b * NKV + kvh;

  // bins: j=0..8 -> single {15-j}; j=9..11 -> {15-j, j-9}; j=12 -> {3}
  const int qt0 = 15 - j;
  const int qt1 = (j >= 9 && j <= 11) ? (j - 9) : -1;
  const int m0 = qt0 + 1;
  const int m1 = (qt1 >= 0) ? qt1 + 1 : 0;
  const int tot = m0 + m1;

  __shared__ unsigned short kls[2][2][4096];  // [group][buf]
  __shared__ unsigned short vls[2][2][4096];
  __shared__ float licomb[256];

  const unsigned short* qptr = qbuf + ((size_t)b * NH + h) * TT * HD;
  const int row0 = qt0 * 128 + wq * 32 + ln;
  const int row1 = ((qt1 >= 0) ? qt1 : 0) * 128 + wq * 32 + ln;

  // Q fragments: statically named sets (constant indices only; rule #20)
  bf16x8 qf0[4], qf1[4], qc[4];
#pragma unroll
  for (int ds = 0; ds < 4; ++ds) {
    qf0[ds] = *(const bf16x8*)(qptr + (size_t)row0 * HD + ds * 16 + hi * 8);
    qf1[ds] = *(const bf16x8*)(qptr + (size_t)row1 * HD + ds * 16 + hi * 8);
  }
  qc[0] = qf0[0]; qc[1] = qf0[1]; qc[2] = qf0[2]; qc[3] = qf0[3];
  int qt_c = qt0, qrow_c = row0, nt_c = m0;

  const char* kgb = (const char*)(kst + head * 32 * 4096);
  const char* vgb = (const char*)(vst + head * 32 * 4096);

  f32x16 o0, o1, fzero;
  float ls[16];
#pragma unroll
  for (int r = 0; r < 16; ++r) { o0[r] = 0.f; o1[r] = 0.f; ls[r] = 0.f; fzero[r] = 0.f; }

  // prologue: stage lockstep iter 0 (kv tile g) into buf 0
  {
    const size_t tb = (size_t)g * 8192;
#pragma unroll
    for (int i2 = 0; i2 < 2; ++i2) {
      const int off = wq * 2048 + i2 * 1024;
      gl16(kgb + tb + off + l * 16, (char*)&kls[g][0][0] + off);
      gl16(vgb + tb + off + l * 16, (char*)&vls[g][0][0] + off);
    }
  }

  int jt = 0;  // lockstep iter within current segment

  for (int it = 0; it < tot; ++it) {
    if (it + 1 < tot) {  // stage lockstep it+1 into other buf (1-ahead)
      const int f = it + 1;
      const int u = (f < m0) ? f : f - m0;
      const size_t tb = (size_t)(2 * u + g) * 8192;
      char* kl = (char*)&kls[g][(it + 1) & 1][0];
      char* vl = (char*)&vls[g][(it + 1) & 1][0];
#pragma unroll
      for (int i2 = 0; i2 < 2; ++i2) {
        const int off = wq * 2048 + i2 * 1024;
        gl16(kgb + tb + off + l * 16, kl + off);
        gl16(vgb + tb + off + l * 16, vl + off);
      }
      asm volatile("s_waitcnt vmcnt(4)" ::: "memory");  // stage(it) done (mine)
    } else {
      asm volatile("s_waitcnt vmcnt(0)" ::: "memory");
    }
    __builtin_amdgcn_s_barrier();          // everyone's stage(it) landed
    __builtin_amdgcn_sched_barrier(0);

    const char* kb = (const char*)&kls[g][it & 1][0];
    const char* vb = (const char*)&vls[g][it & 1][0];

    // QK^T swapped: S^T[k, q]; fragment-major reads (seg base + l*16)
    f32x16 s0, s1;
    __builtin_amdgcn_s_setprio(1);
    {
      bf16x8 k0 = *(const bf16x8*)(kb + 0 * 1024 + l * 16);
      bf16x8 k1 = *(const bf16x8*)(kb + 1 * 1024 + l * 16);
      s0 = MFMA32(k0, qc[0], fzero);
      s1 = MFMA32(k1, qc[0], fzero);
    }
#pragma unroll
    for (int ds = 1; ds < 4; ++ds) {
      bf16x8 k0 = *(const bf16x8*)(kb + (ds * 2 + 0) * 1024 + l * 16);
      bf16x8 k1 = *(const bf16x8*)(kb + (ds * 2 + 1) * 1024 + l * 16);
      s0 = MFMA32(k0, qc[ds], s0);
      s1 = MFMA32(k1, qc[ds], s1);
    }
    __builtin_amdgcn_s_setprio(0);

    const bool segEnd = (jt == qt_c);
    if (segEnd) {  // diagonal lockstep iter: causal mask (elementwise)
      const int kvt = 2 * qt_c + g;
#pragma unroll
      for (int r = 0; r < 16; ++r) {
        const int kg = kvt * 64 + (r & 3) + 8 * (r >> 2) + 4 * hi;
        if (kg > qrow_c) s0[r] = -1e30f;
        if (kg + 32 > qrow_c) s1[r] = -1e30f;
      }
    }

    // static-max softmax: P = exp2(S) directly (S bounded ~|9|); masked -> 0
#pragma unroll
    for (int r = 0; r < 16; ++r) {
      s0[r] = fexp2(s0[r]);
      s1[r] = fexp2(s1[r]);
    }
#pragma unroll
    for (int r = 0; r < 16; ++r) ls[r] += s0[r] + s1[r];

    // pack P -> PV A-fragments: 16 cvt_pk + 8 permlane32_swap
    unsigned int pa[4][4];
#pragma unroll
    for (int t = 0; t < 2; ++t) {
#pragma unroll
      for (int m = 0; m < 2; ++m) {
        float p0 = t ? s1[8 * m + 0] : s0[8 * m + 0];
        float p1 = t ? s1[8 * m + 1] : s0[8 * m + 1];
        float p2 = t ? s1[8 * m + 2] : s0[8 * m + 2];
        float p3 = t ? s1[8 * m + 3] : s0[8 * m + 3];
        float p4 = t ? s1[8 * m + 4] : s0[8 * m + 4];
        float p5 = t ? s1[8 * m + 5] : s0[8 * m + 5];
        float p6 = t ? s1[8 * m + 6] : s0[8 * m + 6];
        float p7 = t ? s1[8 * m + 7] : s0[8 * m + 7];
        unsigned int w0, w1, w2, w3;
        asm("v_cvt_pk_bf16_f32 %0, %1, %2" : "=v"(w0) : "v"(p0), "v"(p1));
        asm("v_cvt_pk_bf16_f32 %0, %1, %2" : "=v"(w1) : "v"(p2), "v"(p3));
        asm("v_cvt_pk_bf16_f32 %0, %1, %2" : "=v"(w2) : "v"(p4), "v"(p5));
        asm("v_cvt_pk_bf16_f32 %0, %1, %2" : "=v"(w3) : "v"(p6), "v"(p7));
        asm("v_permlane32_swap_b32 %0, %1" : "+v"(w0), "+v"(w2));
        asm("v_permlane32_swap_b32 %0, %1" : "+v"(w1), "+v"(w3));
        pa[2 * t + m][0] = w0; pa[2 * t + m][1] = w1;
        pa[2 * t + m][2] = w2; pa[2 * t + m][3] = w3;
      }
    }

    // PV: O[q, d] += P[q, k] V[k, d]; fragment-major reads
    __builtin_amdgcn_s_setprio(1);
#pragma unroll
    for (int ks = 0; ks < 4; ++ks) {
      union { unsigned int u[4]; bf16x8 v; } cvt;
      cvt.u[0] = pa[ks][0]; cvt.u[1] = pa[ks][1];
      cvt.u[2] = pa[ks][2]; cvt.u[3] = pa[ks][3];
      bf16x8 v0 = *(const bf16x8*)(vb + (ks * 2 + 0) * 1024 + l * 16);
      bf16x8 v1 = *(const bf16x8*)(vb + (ks * 2 + 1) * 1024 + l * 16);
      o0 = MFMA32(cvt.v, v0, o0);
      o1 = MFMA32(cvt.v, v1, o1);
    }
    __builtin_amdgcn_s_setprio(0);

    if (segEnd) {
      // combine group partials via LDS scratch = just-consumed buf (it&1)
#pragma unroll
      for (int st = 8; st >= 1; st >>= 1)
#pragma unroll
        for (int r = 0; r < 8; ++r)
          if (r < st) ls[r] += ls[r + st];
      const float tm0 = ls[0] + __shfl_xor(ls[0], 32);
      char* chunk;
      {
        const int buf = it & 1;
        chunk = (char*)((wq == 0) ? &kls[0][buf][0]
               : (wq == 1) ? &vls[0][buf][0]
               : (wq == 2) ? &kls[1][buf][0]
                           : &vls[1][buf][0]);
      }
      __syncthreads();   // all 8 waves done reading buf (it&1)
      if (g == 1) {
#pragma unroll
        for (int r = 0; r < 16; ++r) {
          *(float*)(chunk + r * 256 + l * 4) = o0[r];
          *(float*)(chunk + (16 + r) * 256 + l * 4) = o1[r];
        }
        licomb[wq * 64 + l] = tm0;
      }
      __syncthreads();
      if (g == 0) {
#pragma unroll
        for (int r = 0; r < 16; ++r) {
          o0[r] += *(const float*)(chunk + r * 256 + l * 4);
          o1[r] += *(const float*)(chunk + (16 + r) * 256 + l * 4);
        }
        const float li = tm0 + licomb[wq * 64 + l];
        const float inv = 1.0f / li;
#pragma unroll
        for (int r = 0; r < 16; ++r) {
          const int cr = (r & 3) + 8 * (r >> 2) + 4 * hi;
          const float ir = __shfl(inv, cr);
          const int t = qt_c * 128 + wq * 32 + cr;
          unsigned short* yp = yb + ((size_t)b * TT + t) * CC + h * HD;
          yp[ln] = f2bf(o0[r] * ir);
          yp[32 + ln] = f2bf(o1[r] * ir);
        }
      }
#pragma unroll
      for (int r = 0; r < 16; ++r) { o0[r] = 0.f; o1[r] = 0.f; ls[r] = 0.f; }
    }

    __builtin_amdgcn_sched_barrier(0);
    __builtin_amdgcn_s_barrier();          // readers done before next overwrite
    __builtin_amdgcn_sched_barrier(0);

    // advance segment cursor (wave-uniform; static copies only)
    ++jt;
    if (jt == nt_c && it + 1 < tot) {
      jt = 0;
      qt_c = qt1; qrow_c = row1; nt_c = m1;
      qc[0] = qf1[0]; qc[1] = qf1[1]; qc[2] = qf1[2]; qc[3] = qf1[3];
    }
  }
}

// ---------------------------------------------------------------------------
// GEMM2: BM=256 BN=64, 8 waves, staged structure; f32 epilogue.
// ---------------------------------------------------------------------------
__global__ __launch_bounds__(512, 4) void gemm_out(
    const unsigned short* __restrict__ yb, const unsigned short* __restrict__ woh,
    float* __restrict__ out) {
  const int l = threadIdx.x & 63, w = threadIdx.x >> 6;
  const int ln = l & 31, hi = l >> 5;
  const int bm = blockIdx.y * 256, bn = blockIdx.x * 64;

  __shared__ unsigned short als[2][16384];
  __shared__ unsigned short bls[2][4096];

  int asrc[4];
#pragma unroll
  for (int i = 0; i < 4; ++i)
    asrc[i] = (bm + w * 32 + i * 8 + (l >> 3)) * CC + ((l & 7) ^ ((l >> 3) & 7)) * 8;
  const int bsrc = (bn + w * 8 + (l >> 3)) * CC + ((l & 7) ^ ((l >> 3) & 7)) * 8;

  f32x16 acc0, acc1;
#pragma unroll
  for (int r = 0; r < 16; ++r) { acc0[r] = 0.f; acc1[r] = 0.f; }

#pragma unroll
  for (int i = 0; i < 4; ++i) gl16(yb + asrc[i], (char*)&als[0][0] + w * 4096 + i * 1024);
  gl16(woh + bsrc, (char*)&bls[0][0] + w * 1024);

  int cur = 0;
  for (int t = 0; t < 9; ++t) {
    if (t + 1 < 9) {
      const int k0 = (t + 1) * 64;
#pragma unroll
      for (int i = 0; i < 4; ++i)
        gl16(yb + asrc[i] + k0, (char*)&als[cur ^ 1][0] + w * 4096 + i * 1024);
      gl16(woh + bsrc + k0, (char*)&bls[cur ^ 1][0] + w * 1024);
      asm volatile("s_waitcnt vmcnt(5)" ::: "memory");
    } else {
      asm volatile("s_waitcnt vmcnt(0)" ::: "memory");
    }
    __builtin_amdgcn_s_barrier();
    __builtin_amdgcn_sched_barrier(0);

    const char* ab = (const char*)&als[cur][0];
    const char* bb = (const char*)&bls[cur][0];
    __builtin_amdgcn_s_setprio(1);
#pragma unroll
    for (int ks = 0; ks < 4; ++ks) {
      const int ch = (((ks * 2 + hi) ^ (ln & 7)) << 4);
      bf16x8 af = *(const bf16x8*)(ab + (w * 32 + ln) * 128 + ch);
      bf16x8 b0 = *(const bf16x8*)(bb + ln * 128 + ch);
      bf16x8 b1 = *(const bf16x8*)(bb + (32 + ln) * 128 + ch);
      acc0 = MFMA32(af, b0, acc0);
      acc1 = MFMA32(af, b1, acc1);
    }
    __builtin_amdgcn_s_setprio(0);

    __builtin_amdgcn_sched_barrier(0);
    __builtin_amdgcn_s_barrier();
    cur ^= 1;
  }

#pragma unroll
  for (int n32 = 0; n32 < 2; ++n32) {
    const int col = bn + n32 * 32 + ln;
#pragma unroll
    for (int r = 0; r < 16; ++r) {
      const int m = bm + w * 32 + (r & 3) + 8 * (r >> 2) + 4 * hi;
      out[(size_t)m * CC + col] = n32 ? acc1[r] : acc0[r];
    }
  }
}

// ---------------------------------------------------------------------------
extern "C" void kernel_launch(void* const* d_in, const int* in_sizes, int n_in,
                              void* d_out, int out_size, void* d_ws, size_t ws_size,
                              hipStream_t stream) {
  const float* x = (const float*)d_in[0];
  const float* wq = (const float*)d_in[1];
  const float* wk = (const float*)d_in[2];
  const float* wv = (const float*)d_in[3];
  const float* wo = (const float*)d_in[4];
  float* out = (float*)d_out;

  char* ws = (char*)d_ws;
  unsigned short* xh = (unsigned short*)ws;    ws += (size_t)MM * CC * 2;
  unsigned short* wqkv = (unsigned short*)ws;  ws += (size_t)NQKV * CC * 2;
  float* tc = (float*)ws;                      ws += (size_t)TT * 32 * 4;
  float* tsn = (float*)ws;                     ws += (size_t)TT * 32 * 4;
  unsigned short* woh = (unsigned short*)ws;   ws += (size_t)CC * CC * 2;
  unsigned short* qbuf = (unsigned short*)ws;  ws += (size_t)BB * NH * TT * HD * 2;
  unsigned short* kst = (unsigned short*)ws;   ws += (size_t)BB * NKV * TT * HD * 2;
  unsigned short* vst = (unsigned short*)ws;   ws += (size_t)BB * NKV * HD * TT * 2;
  unsigned short* yb = (unsigned short*)ws;    ws += (size_t)MM * CC * 2;

  prep_kernel<<<dim3(2048), dim3(256), 0, stream>>>(x, wq, wk, wv, wo, xh, wqkv, woh, tc, tsn);
  gemm_qkv<<<dim3(NQKV / 64, MM / 256), dim3(512), 0, stream>>>(xh, wqkv, tc, tsn, qbuf, kst, vst);
  attn_kernel<<<dim3(39, NKV, BB), dim3(512), 0, stream>>>(qbuf, kst, vst, yb);
  gemm_out<<<dim3(CC / 64, MM / 256), dim3(512), 0, stream>>>(yb, woh, out);
}